// Round 1
// baseline (71.616 us; speedup 1.0000x reference)
//
#include <hip/hip_runtime.h>
#include <cstdint>

#define NN 4096
#define FF 512

typedef short bf16x8 __attribute__((ext_vector_type(8)));
typedef float f32x4 __attribute__((ext_vector_type(4)));

__device__ __forceinline__ uint16_t f2bf(float f) {
    uint32_t u = __builtin_bit_cast(uint32_t, f);
    u += 0x7FFFu + ((u >> 16) & 1u);   // round-to-nearest-even
    return (uint16_t)(u >> 16);
}

// ---------------------------------------------------------------------------
// k_prep: A_bf[i][j] = bf16( d_i * (adj[i][j] + (i==j)) ), d_i = rsqrt(1 + rowsum)
// One wave per row; row (16 KB) kept in registers so adj is read exactly once.
// ---------------------------------------------------------------------------
__global__ __launch_bounds__(256) void k_prep(const float* __restrict__ adj,
                                              float* __restrict__ d,
                                              uint16_t* __restrict__ Abf) {
    const int row  = blockIdx.x * 4 + (threadIdx.x >> 6);
    const int lane = threadIdx.x & 63;
    const float4* p = (const float4*)(adj + (size_t)row * NN);
    float4 v[16];
    float s = 0.f;
#pragma unroll
    for (int i = 0; i < 16; ++i) {
        v[i] = p[lane + i * 64];
        s += (v[i].x + v[i].y) + (v[i].z + v[i].w);
    }
#pragma unroll
    for (int off = 1; off < 64; off <<= 1) s += __shfl_xor(s, off);
    const float di = rsqrtf(s + 1.0f);
    if (lane == 0) d[row] = di;
    uint16_t* outp = Abf + (size_t)row * NN;
#pragma unroll
    for (int i = 0; i < 16; ++i) {
        const int cb = (lane + i * 64) * 4;
        float a0 = v[i].x * di, a1 = v[i].y * di, a2 = v[i].z * di, a3 = v[i].w * di;
        if (cb + 0 == row) a0 += di;
        if (cb + 1 == row) a1 += di;
        if (cb + 2 == row) a2 += di;
        if (cb + 3 == row) a3 += di;
        ushort4 o;
        o.x = f2bf(a0); o.y = f2bf(a1); o.z = f2bf(a2); o.w = f2bf(a3);
        *(ushort4*)(outp + cb) = o;
    }
}

// ---------------------------------------------------------------------------
// k_xt: yT[n][k] = bf16(d[k] * x[k][n])   (x: [4096][512] f32 -> yT: [512][4096] bf16)
// 64x64 tile transpose through LDS; writes are 16B coalesced.
// ---------------------------------------------------------------------------
__global__ __launch_bounds__(256) void k_xt(const float* __restrict__ x,
                                            const float* __restrict__ d,
                                            uint16_t* __restrict__ yT) {
    __shared__ uint16_t t[64][72];   // 72: keeps 16B alignment of row starts (144 B = 9*16)
    const int k0 = blockIdx.x * 64;
    const int n0 = blockIdx.y * 64;
    const int tid = threadIdx.x;
    const int r   = tid >> 4;
    const int c4  = tid & 15;
#pragma unroll
    for (int pass = 0; pass < 4; ++pass) {
        const int row = pass * 16 + r;   // k within tile
        float4 v = *(const float4*)(x + (size_t)(k0 + row) * FF + n0 + c4 * 4);
        const float dk = d[k0 + row];
        t[c4 * 4 + 0][row] = f2bf(v.x * dk);
        t[c4 * 4 + 1][row] = f2bf(v.y * dk);
        t[c4 * 4 + 2][row] = f2bf(v.z * dk);
        t[c4 * 4 + 3][row] = f2bf(v.w * dk);
    }
    __syncthreads();
#pragma unroll
    for (int pass = 0; pass < 2; ++pass) {
        const int cid = pass * 256 + tid;
        const int n  = cid >> 3;
        const int ch = cid & 7;
        *(uint4*)(yT + (size_t)(n0 + n) * NN + k0 + ch * 8) = *(const uint4*)&t[n][ch * 8];
    }
}

// ---------------------------------------------------------------------------
// k_wc: W (f32 [512][512], already [N][K] for h @ W^T) -> bf16
// ---------------------------------------------------------------------------
__global__ __launch_bounds__(256) void k_wc(const float* __restrict__ W,
                                            uint16_t* __restrict__ Wbf) {
    const size_t t4 = (size_t)blockIdx.x * 256 + threadIdx.x;
    float4 v = *(const float4*)(W + t4 * 4);
    ushort4 o;
    o.x = f2bf(v.x); o.y = f2bf(v.y); o.z = f2bf(v.z); o.w = f2bf(v.w);
    *(ushort4*)(Wbf + t4 * 4) = o;
}

// ---------------------------------------------------------------------------
// k_gemm: C[M=4096][512] = A[M][K] * Bt[512][K]^T  (both bf16, K-contiguous rows)
// BM=BN=BK=64, 256 threads (4 waves 2x2), mfma_f32_16x16x32_bf16, acc 2x2 frags.
// Staging: global_load_lds 16B with inverse-swizzled global source; ds_read_b128
// with chunk ^= (row&7) swizzle -> 2 lanes/bank (free).
// ---------------------------------------------------------------------------
template <int K, bool OUT_BF16>
__global__ __launch_bounds__(256, 2) void k_gemm(const uint16_t* __restrict__ A,
                                                 const uint16_t* __restrict__ Bt,
                                                 const float* __restrict__ bias,
                                                 uint16_t* __restrict__ outb,
                                                 float* __restrict__ outf) {
    __shared__ uint16_t As[64 * 64];
    __shared__ uint16_t Bs[64 * 64];

    // XCD-bijective swizzle: 512 blocks, id%8 = XCD; each XCD owns 8 consecutive
    // m-tiles across all 8 n-tiles -> A row-stripes stay L2-resident per XCD.
    const int id   = blockIdx.x;
    const int xcd  = id & 7;
    const int slot = id >> 3;           // 0..63
    const int n_t  = slot & 7;
    const int m_t  = xcd * 8 + (slot >> 3);
    const int m0 = m_t * 64;
    const int n0 = n_t * 64;

    const int tid  = threadIdx.x;
    const int w    = tid >> 6;
    const int lane = tid & 63;
    const int wm = w >> 1, wn = w & 1;

    f32x4 acc[2][2] = {};

    for (int kt = 0; kt < K / 64; ++kt) {
        __syncthreads();   // previous compute done before overwriting LDS
#pragma unroll
        for (int i = 0; i < 2; ++i) {
            const int boff = w * 2048 + i * 1024 + lane * 16;  // byte within 8KB tile
            const int row  = boff >> 7;                        // 0..63
            const int q    = (boff >> 4) & 7;                  // chunk slot in LDS
            const int c    = q ^ (row & 7);                    // global chunk held there
            const uint16_t* srcA = A  + (size_t)(m0 + row) * K + kt * 64 + c * 8;
            const uint16_t* srcB = Bt + (size_t)(n0 + row) * K + kt * 64 + c * 8;
            __builtin_amdgcn_global_load_lds(
                (const __attribute__((address_space(1))) void*)srcA,
                (__attribute__((address_space(3))) void*)&As[(w * 2048 + i * 1024) >> 1],
                16, 0, 0);
            __builtin_amdgcn_global_load_lds(
                (const __attribute__((address_space(1))) void*)srcB,
                (__attribute__((address_space(3))) void*)&Bs[(w * 2048 + i * 1024) >> 1],
                16, 0, 0);
        }
        __syncthreads();   // drains vmcnt -> staged data visible

#pragma unroll
        for (int kk = 0; kk < 2; ++kk) {
            bf16x8 af[2], bfr[2];
#pragma unroll
            for (int mf = 0; mf < 2; ++mf) {
                const int m  = wm * 32 + mf * 16 + (lane & 15);
                const int ch = (kk * 4 + (lane >> 4)) ^ (m & 7);
                af[mf] = *(const bf16x8*)&As[m * 64 + ch * 8];
            }
#pragma unroll
            for (int nf = 0; nf < 2; ++nf) {
                const int n  = wn * 32 + nf * 16 + (lane & 15);
                const int ch = (kk * 4 + (lane >> 4)) ^ (n & 7);
                bfr[nf] = *(const bf16x8*)&Bs[n * 64 + ch * 8];
            }
#pragma unroll
            for (int mf = 0; mf < 2; ++mf)
#pragma unroll
                for (int nf = 0; nf < 2; ++nf)
                    acc[mf][nf] = __builtin_amdgcn_mfma_f32_16x16x32_bf16(
                        af[mf], bfr[nf], acc[mf][nf], 0, 0, 0);
        }
    }

    // epilogue: C/D layout col = lane&15, row = (lane>>4)*4 + r  [m89-verified]
#pragma unroll
    for (int mf = 0; mf < 2; ++mf) {
#pragma unroll
        for (int nf = 0; nf < 2; ++nf) {
            const int rbase = m0 + wm * 32 + mf * 16 + ((lane >> 4) << 2);
            const int col   = n0 + wn * 32 + nf * 16 + (lane & 15);
#pragma unroll
            for (int r = 0; r < 4; ++r) {
                const size_t idx = (size_t)(rbase + r) * FF + col;
                if constexpr (OUT_BF16) {
                    outb[idx] = f2bf(acc[mf][nf][r]);
                } else {
                    outf[idx] = acc[mf][nf][r] + bias[col];
                }
            }
        }
    }
}

// ---------------------------------------------------------------------------
extern "C" void kernel_launch(void* const* d_in, const int* in_sizes, int n_in,
                              void* d_out, int out_size, void* d_ws, size_t ws_size,
                              hipStream_t stream) {
    const float* x   = (const float*)d_in[0];   // [4096][512]
    const float* adj = (const float*)d_in[1];   // [4096][4096]
    const float* W   = (const float*)d_in[2];   // [512][512]
    const float* b   = (const float*)d_in[3];   // [512]
    float* out = (float*)d_out;                 // [4096][512] f32

    char* ws = (char*)d_ws;
    float*    d_   = (float*)ws;                                  // 16 KB
    uint16_t* Abf  = (uint16_t*)(ws + 65536);                     // 32 MB
    uint16_t* yT   = Abf + (size_t)NN * NN;                       // 4 MB
    uint16_t* hbf  = yT  + (size_t)FF * NN;                       // 4 MB
    uint16_t* Wbf  = hbf + (size_t)NN * FF;                       // 0.5 MB

    k_prep<<<NN / 4, 256, 0, stream>>>(adj, d_, Abf);
    k_xt<<<dim3(NN / 64, FF / 64), 256, 0, stream>>>(x, d_, yT);
    k_wc<<<FF * FF / 4 / 256, 256, 0, stream>>>(W, Wbf);
    k_gemm<NN, true><<<(NN / 64) * (FF / 64), 256, 0, stream>>>(Abf, yT, nullptr, hbf, nullptr);
    k_gemm<FF, false><<<(NN / 64) * (FF / 64), 256, 0, stream>>>(hbf, Wbf, b, nullptr, out);
}

// Round 2
// 69.977 us; speedup vs baseline: 1.0234x; 1.0234x over previous
//
#include <hip/hip_runtime.h>
#include <cstdint>

#define NN 4096
#define FF 512

typedef short bf16x8 __attribute__((ext_vector_type(8)));
typedef float f32x4 __attribute__((ext_vector_type(4)));

__device__ __forceinline__ uint16_t f2bf(float f) {
    uint32_t u = __builtin_bit_cast(uint32_t, f);
    u += 0x7FFFu + ((u >> 16) & 1u);   // round-to-nearest-even
    return (uint16_t)(u >> 16);
}

// ---------------------------------------------------------------------------
// k_prep: A_bf[i][j] = bf16( d_i * (adj[i][j] + (i==j)) ), d_i = rsqrt(1 + rowsum)
// One wave per row; row (16 KB) kept in registers so adj is read exactly once.
// ---------------------------------------------------------------------------
__global__ __launch_bounds__(256) void k_prep(const float* __restrict__ adj,
                                              float* __restrict__ d,
                                              uint16_t* __restrict__ Abf) {
    const int row  = blockIdx.x * 4 + (threadIdx.x >> 6);
    const int lane = threadIdx.x & 63;
    const float4* p = (const float4*)(adj + (size_t)row * NN);
    float4 v[16];
    float s = 0.f;
#pragma unroll
    for (int i = 0; i < 16; ++i) {
        v[i] = p[lane + i * 64];
        s += (v[i].x + v[i].y) + (v[i].z + v[i].w);
    }
#pragma unroll
    for (int off = 1; off < 64; off <<= 1) s += __shfl_xor(s, off);
    const float di = rsqrtf(s + 1.0f);
    if (lane == 0) d[row] = di;
    uint16_t* outp = Abf + (size_t)row * NN;
#pragma unroll
    for (int i = 0; i < 16; ++i) {
        const int cb = (lane + i * 64) * 4;
        float a0 = v[i].x * di, a1 = v[i].y * di, a2 = v[i].z * di, a3 = v[i].w * di;
        if (cb + 0 == row) a0 += di;
        if (cb + 1 == row) a1 += di;
        if (cb + 2 == row) a2 += di;
        if (cb + 3 == row) a3 += di;
        ushort4 o;
        o.x = f2bf(a0); o.y = f2bf(a1); o.z = f2bf(a2); o.w = f2bf(a3);
        *(ushort4*)(outp + cb) = o;
    }
}

// ---------------------------------------------------------------------------
// k_xt: yT[n][k] = bf16(d[k] * x[k][n])   (x: [4096][512] f32 -> yT: [512][4096] bf16)
// ---------------------------------------------------------------------------
__global__ __launch_bounds__(256) void k_xt(const float* __restrict__ x,
                                            const float* __restrict__ d,
                                            uint16_t* __restrict__ yT) {
    __shared__ uint16_t t[64][72];
    const int k0 = blockIdx.x * 64;
    const int n0 = blockIdx.y * 64;
    const int tid = threadIdx.x;
    const int r   = tid >> 4;
    const int c4  = tid & 15;
#pragma unroll
    for (int pass = 0; pass < 4; ++pass) {
        const int row = pass * 16 + r;
        float4 v = *(const float4*)(x + (size_t)(k0 + row) * FF + n0 + c4 * 4);
        const float dk = d[k0 + row];
        t[c4 * 4 + 0][row] = f2bf(v.x * dk);
        t[c4 * 4 + 1][row] = f2bf(v.y * dk);
        t[c4 * 4 + 2][row] = f2bf(v.z * dk);
        t[c4 * 4 + 3][row] = f2bf(v.w * dk);
    }
    __syncthreads();
#pragma unroll
    for (int pass = 0; pass < 2; ++pass) {
        const int cid = pass * 256 + tid;
        const int n  = cid >> 3;
        const int ch = cid & 7;
        *(uint4*)(yT + (size_t)(n0 + n) * NN + k0 + ch * 8) = *(const uint4*)&t[n][ch * 8];
    }
}

// ---------------------------------------------------------------------------
// k_wc: W (f32 [512][512]) -> bf16
// ---------------------------------------------------------------------------
__global__ __launch_bounds__(256) void k_wc(const float* __restrict__ W,
                                            uint16_t* __restrict__ Wbf) {
    const size_t t4 = (size_t)blockIdx.x * 256 + threadIdx.x;
    float4 v = *(const float4*)(W + t4 * 4);
    ushort4 o;
    o.x = f2bf(v.x); o.y = f2bf(v.y); o.z = f2bf(v.z); o.w = f2bf(v.w);
    *(ushort4*)(Wbf + t4 * 4) = o;
}

// ---------------------------------------------------------------------------
// k_gemm: C[4096][512] = A[4096][K] * Bt[512][K]^T  (bf16, K-contiguous rows)
// BM=BN=BK=64, 4 waves (2x2), mfma_f32_16x16x32_bf16, acc 2x2 frags.
// T3+T4: DEPTH=4 LDS ring (64KB), prefetch 3 tiles ahead via global_load_lds,
// counted vmcnt(12) + raw s_barrier — never drains to 0 in the main loop.
// LDS chunk swizzle: chunk ^= (row&7) (inverse-swizzled global src, rule #21).
// ---------------------------------------------------------------------------
template <int K, bool OUT_BF16>
__global__ __launch_bounds__(256, 2) void k_gemm(const uint16_t* __restrict__ A,
                                                 const uint16_t* __restrict__ Bt,
                                                 const float* __restrict__ bias,
                                                 uint16_t* __restrict__ outb,
                                                 float* __restrict__ outf) {
    constexpr int NT = K / 64;
    __shared__ uint16_t As[4][64 * 64];
    __shared__ uint16_t Bs[4][64 * 64];

    // XCD-bijective swizzle: 512 blocks, id%8 = XCD; each XCD owns 8 consecutive
    // m-tiles across all 8 n-tiles -> A row-stripes stay L2-resident per XCD.
    const int id   = blockIdx.x;
    const int xcd  = id & 7;
    const int slot = id >> 3;
    const int n_t  = slot & 7;
    const int m_t  = xcd * 8 + (slot >> 3);
    const int m0 = m_t * 64;
    const int n0 = n_t * 64;

    const int tid  = threadIdx.x;
    const int w    = tid >> 6;
    const int lane = tid & 63;
    const int wm = w >> 1, wn = w & 1;

    f32x4 acc[2][2] = {};

    auto STAGE = [&](int t, int buf) {
#pragma unroll
        for (int i = 0; i < 2; ++i) {
            const int boff = w * 2048 + i * 1024 + lane * 16;  // byte within 8KB tile
            const int row  = boff >> 7;                        // 0..63
            const int q    = (boff >> 4) & 7;                  // chunk slot in LDS
            const int c    = q ^ (row & 7);                    // global chunk held there
            const uint16_t* srcA = A  + (size_t)(m0 + row) * K + t * 64 + c * 8;
            const uint16_t* srcB = Bt + (size_t)(n0 + row) * K + t * 64 + c * 8;
            __builtin_amdgcn_global_load_lds(
                (const __attribute__((address_space(1))) void*)srcA,
                (__attribute__((address_space(3))) void*)&As[buf][(w * 2048 + i * 1024) >> 1],
                16, 0, 0);
            __builtin_amdgcn_global_load_lds(
                (const __attribute__((address_space(1))) void*)srcB,
                (__attribute__((address_space(3))) void*)&Bs[buf][(w * 2048 + i * 1024) >> 1],
                16, 0, 0);
        }
    };

    auto COMPUTE = [&](int buf) {
#pragma unroll
        for (int kk = 0; kk < 2; ++kk) {
            bf16x8 af[2], bfr[2];
#pragma unroll
            for (int mf = 0; mf < 2; ++mf) {
                const int m  = wm * 32 + mf * 16 + (lane & 15);
                const int ch = (kk * 4 + (lane >> 4)) ^ (m & 7);
                af[mf] = *(const bf16x8*)&As[buf][m * 64 + ch * 8];
            }
#pragma unroll
            for (int nf = 0; nf < 2; ++nf) {
                const int n  = wn * 32 + nf * 16 + (lane & 15);
                const int ch = (kk * 4 + (lane >> 4)) ^ (n & 7);
                bfr[nf] = *(const bf16x8*)&Bs[buf][n * 64 + ch * 8];
            }
#pragma unroll
            for (int mf = 0; mf < 2; ++mf)
#pragma unroll
                for (int nf = 0; nf < 2; ++nf)
                    acc[mf][nf] = __builtin_amdgcn_mfma_f32_16x16x32_bf16(
                        af[mf], bfr[nf], acc[mf][nf], 0, 0, 0);
        }
    };

    // prologue: 3 tiles in flight (12 loads/wave outstanding)
    STAGE(0, 0);
    STAGE(1, 1);
    STAGE(2, 2);

    // main loop: stage t+3, wait own 4 oldest loads (tile t), barrier, compute.
    // vmcnt(12) leaves tiles t+1,t+2,t+3 (12 loads) in flight across barriers.
    for (int t = 0; t < NT - 3; ++t) {
        STAGE(t + 3, (t + 3) & 3);
        asm volatile("s_waitcnt vmcnt(12)" ::: "memory");
        __builtin_amdgcn_s_barrier();
        COMPUTE(t & 3);
        __builtin_amdgcn_s_barrier();   // protect buf (t+4)&3 = (t)&3 overwrite next iter
    }
    // tail: drain 8 -> 4 -> 0 (no LDS writes remain, so no end barriers needed)
    asm volatile("s_waitcnt vmcnt(8)" ::: "memory");
    __builtin_amdgcn_s_barrier();
    COMPUTE((NT - 3) & 3);
    asm volatile("s_waitcnt vmcnt(4)" ::: "memory");
    __builtin_amdgcn_s_barrier();
    COMPUTE((NT - 2) & 3);
    asm volatile("s_waitcnt vmcnt(0)" ::: "memory");
    __builtin_amdgcn_s_barrier();
    COMPUTE((NT - 1) & 3);

    // epilogue: C/D layout col = lane&15, row = (lane>>4)*4 + r  [m89-verified]
#pragma unroll
    for (int mf = 0; mf < 2; ++mf) {
#pragma unroll
        for (int nf = 0; nf < 2; ++nf) {
            const int rbase = m0 + wm * 32 + mf * 16 + ((lane >> 4) << 2);
            const int col   = n0 + wn * 32 + nf * 16 + (lane & 15);
#pragma unroll
            for (int r = 0; r < 4; ++r) {
                const size_t idx = (size_t)(rbase + r) * FF + col;
                if constexpr (OUT_BF16) {
                    outb[idx] = f2bf(acc[mf][nf][r]);
                } else {
                    outf[idx] = acc[mf][nf][r] + bias[col];
                }
            }
        }
    }
}

// ---------------------------------------------------------------------------
extern "C" void kernel_launch(void* const* d_in, const int* in_sizes, int n_in,
                              void* d_out, int out_size, void* d_ws, size_t ws_size,
                              hipStream_t stream) {
    const float* x   = (const float*)d_in[0];   // [4096][512]
    const float* adj = (const float*)d_in[1];   // [4096][4096]
    const float* W   = (const float*)d_in[2];   // [512][512]
    const float* b   = (const float*)d_in[3];   // [512]
    float* out = (float*)d_out;                 // [4096][512] f32

    char* ws = (char*)d_ws;
    float*    d_   = (float*)ws;                                  // 16 KB
    uint16_t* Abf  = (uint16_t*)(ws + 65536);                     // 32 MB
    uint16_t* yT   = Abf + (size_t)NN * NN;                       // 4 MB
    uint16_t* hbf  = yT  + (size_t)FF * NN;                       // 4 MB
    uint16_t* Wbf  = hbf + (size_t)NN * FF;                       // 0.5 MB

    k_prep<<<NN / 4, 256, 0, stream>>>(adj, d_, Abf);
    k_xt<<<dim3(NN / 64, FF / 64), 256, 0, stream>>>(x, d_, yT);
    k_wc<<<FF * FF / 4 / 256, 256, 0, stream>>>(W, Wbf);
    k_gemm<NN, true><<<(NN / 64) * (FF / 64), 256, 0, stream>>>(Abf, yT, nullptr, hbf, nullptr);
    k_gemm<FF, false><<<(NN / 64) * (FF / 64), 256, 0, stream>>>(hbf, Wbf, b, nullptr, out);
}